// Round 1
// baseline (1479.886 us; speedup 1.0000x reference)
//
#include <hip/hip_runtime.h>
#include <math.h>

#define HH 128
#define NPIX 16384         // 128*128
#define BB 8
#define MM 4096
#define NN 16384
#define KC 2
#define LRELU_S 0.1f

__device__ __forceinline__ float leaky_(float v){ return v >= 0.f ? v : LRELU_S*v; }
__device__ __forceinline__ float clamp01(float v){ return fminf(fmaxf(v, 0.f), 1.f); }
__device__ __forceinline__ float clamp02(float v){ return fminf(fmaxf(v, 0.f), 2.f); }

// ---------------- convK: x[B,1,H,W] -> out[B,2,H,W], 3x3 corr, pad 1 ----------------
__global__ __launch_bounds__(256) void k_convK(const float* __restrict__ x,
                                               const float* __restrict__ wK,
                                               float* __restrict__ out){
  int idx = blockIdx.x*256 + threadIdx.x;           // BB*KC*NPIX = 262144
  if (idx >= BB*KC*NPIX) return;
  int j = idx & 127, i = (idx>>7) & 127, c = (idx>>14) & 1, b = idx>>15;
  const float* xb = x + b*NPIX;
  float s = 0.f;
  #pragma unroll
  for (int di=0; di<3; ++di){
    int ii = i + di - 1;
    if ((unsigned)ii >= 128u) continue;
    #pragma unroll
    for (int dj=0; dj<3; ++dj){
      int jj = j + dj - 1;
      if ((unsigned)jj >= 128u) continue;
      s += xb[ii*HH + jj] * wK[(c*3+di)*3 + dj];
    }
  }
  out[idx] = s;
}

// ------------- conv5 residual: out = in + leaky(conv5x5(in)+bias); optional nu fuse -------------
// fuse_nu: out = 2a*(Kx - (in + leaky(conv(in)+bias)))
__global__ __launch_bounds__(256) void k_conv5(const float* __restrict__ in,
                                               const float* __restrict__ w,
                                               const float* __restrict__ bias,
                                               float* __restrict__ out,
                                               const float* __restrict__ Kx,
                                               const float* __restrict__ alpha,
                                               int fuse_nu){
  int idx = blockIdx.x*256 + threadIdx.x;           // BB*KC*NPIX
  if (idx >= BB*KC*NPIX) return;
  int j = idx & 127, i = (idx>>7) & 127, o = (idx>>14) & 1, b = idx>>15;
  const float* inb = in + b*KC*NPIX;
  float s = bias[o];
  #pragma unroll
  for (int c=0; c<KC; ++c){
    const float* pc = inb + c*NPIX;
    const float* wc = w + (o*KC + c)*25;
    #pragma unroll
    for (int di=0; di<5; ++di){
      int ii = i + di - 2;
      if ((unsigned)ii >= 128u) continue;
      #pragma unroll
      for (int dj=0; dj<5; ++dj){
        int jj = j + dj - 2;
        if ((unsigned)jj >= 128u) continue;
        s += pc[ii*HH + jj] * wc[di*5 + dj];
      }
    }
  }
  float p = in[idx] + leaky_(s);
  if (fuse_nu){
    float a = clamp02(alpha[0]);
    out[idx] = 2.f*a*(Kx[idx] - p);
  } else {
    out[idx] = p;
  }
}

// ------------- convKt: nu[B,2,H,W] -> rk[B,1,H,W]; adjoint of convK -------------
__global__ __launch_bounds__(256) void k_convKt(const float* __restrict__ nu,
                                                const float* __restrict__ wK,
                                                float* __restrict__ rk){
  int idx = blockIdx.x*256 + threadIdx.x;           // BB*NPIX = 131072
  if (idx >= BB*NPIX) return;
  int j = idx & 127, i = (idx>>7) & 127, b = idx>>14;
  float s = 0.f;
  #pragma unroll
  for (int c=0; c<KC; ++c){
    const float* pc = nu + (b*KC + c)*NPIX;
    #pragma unroll
    for (int di=0; di<3; ++di){
      int ii = i + di - 1;
      if ((unsigned)ii >= 128u) continue;
      #pragma unroll
      for (int dj=0; dj<3; ++dj){
        int jj = j + dj - 1;
        if ((unsigned)jj >= 128u) continue;
        s += pc[ii*HH + jj] * wK[(c*3 + (2-di))*3 + (2-dj)];
      }
    }
  }
  rk[idx] = s;
}

// ------------- dn[b] = ||d[b,:]|| -------------
__global__ __launch_bounds__(256) void k_dn(const float* __restrict__ d, float* __restrict__ dn){
  int b = blockIdx.x, t = threadIdx.x;
  float ss = 0.f;
  for (int m=t; m<MM; m+=256){ float v = d[b*MM + m]; ss += v*v; }
  #pragma unroll
  for (int off=32; off; off>>=1) ss += __shfl_down(ss, off);
  __shared__ float red[4];
  if ((t & 63) == 0) red[t>>6] = ss;
  __syncthreads();
  if (t == 0) dn[b] = sqrtf(red[0]+red[1]+red[2]+red[3]);
}

// ------------- GEMM1: y[b,m] += sum_n A[m,n]*x[b,n]  (atomic over n-splits) -------------
#define G1_TM 32
#define G1_NT 1024
#define G1_NS (NN/G1_NT)   // 16
__global__ __launch_bounds__(256) void k_gemm1(const float* __restrict__ A_,
                                               const float* __restrict__ x,
                                               float* __restrict__ y){
  __shared__ float xs[BB][G1_NT];                   // 32 KiB
  int blk = blockIdx.x;                             // (MM/G1_TM)*G1_NS = 2048
  int mblk = blk / G1_NS, nblk = blk % G1_NS;
  int m0 = mblk*G1_TM, n0 = nblk*G1_NT;
  int t = threadIdx.x;
  for (int i=t; i < BB*G1_NT/4; i += 256){
    int b = i >> 8;                                 // G1_NT/4 = 256 float4 per b
    int j4 = i & 255;
    *(float4*)&xs[b][j4*4] = *(const float4*)&x[(size_t)b*NN + n0 + j4*4];
  }
  __syncthreads();
  int r = t >> 3, c = t & 7;
  float acc[BB] = {0.f,0.f,0.f,0.f,0.f,0.f,0.f,0.f};
  const float* Ar = A_ + (size_t)(m0 + r)*NN + n0 + c*4;
  #pragma unroll 4
  for (int k=0; k<G1_NT/32; ++k){
    float4 a4 = *(const float4*)(Ar + k*32);
    #pragma unroll
    for (int b=0; b<BB; ++b){
      const float* xp = &xs[b][c*4 + k*32];
      acc[b] += a4.x*xp[0] + a4.y*xp[1] + a4.z*xp[2] + a4.w*xp[3];
    }
  }
  #pragma unroll
  for (int mask=1; mask<8; mask<<=1)
    #pragma unroll
    for (int b=0; b<BB; ++b) acc[b] += __shfl_xor(acc[b], mask);
  if (c == 0){
    #pragma unroll
    for (int b=0; b<BB; ++b) atomicAdd(&y[b*MM + m0 + r], acc[b]);
  }
}

// ------------- proj: z[b,m] = 2a(1-scale_b)*(y[b,m]-d[b,m]) -------------
__global__ __launch_bounds__(256) void k_proj(const float* __restrict__ y,
                                              const float* __restrict__ d,
                                              const float* __restrict__ dn,
                                              const float* __restrict__ delta,
                                              const float* __restrict__ alpha,
                                              float* __restrict__ z){
  int b = blockIdx.x, t = threadIdx.x;
  float ss = 0.f;
  for (int m=t; m<MM; m+=256){
    float r = y[b*MM + m] - d[b*MM + m];
    z[b*MM + m] = r;
    ss += r*r;
  }
  #pragma unroll
  for (int off=32; off; off>>=1) ss += __shfl_down(ss, off);
  __shared__ float red[4];
  if ((t & 63) == 0) red[t>>6] = ss;
  __syncthreads();
  float dist = fmaxf(sqrtf(red[0]+red[1]+red[2]+red[3]), 1e-10f);
  float de = expf(delta[0]);
  float a  = clamp02(alpha[0]);
  float scale = fminf(1.f, de*dn[b]/dist);
  float coef = 2.f*a*(1.f - scale);
  for (int m=t; m<MM; m+=256) z[b*MM + m] *= coef;
}

// ------------- GEMM2: up[ms][b][n] = sum_{m in split ms} A[m,n]*z[b,m] -------------
#define G2_MS 32
#define G2_MT (MM/G2_MS)   // 128
#define G2_NB 16
#define G2_NT (NN/G2_NB)   // 1024
__global__ __launch_bounds__(256) void k_gemm2(const float* __restrict__ A_,
                                               const float* __restrict__ z,
                                               float* __restrict__ up){
  __shared__ float zs[BB][G2_MT];                   // 4 KiB
  int blk = blockIdx.x;                             // G2_MS*G2_NB = 512
  int ms = blk / G2_NB, nb = blk % G2_NB;
  int mbase = ms*G2_MT, n0 = nb*G2_NT;
  int t = threadIdx.x;
  for (int i=t; i < BB*G2_MT; i += 256){
    int b = i >> 7, ml = i & 127;
    zs[b][ml] = z[b*MM + mbase + ml];
  }
  __syncthreads();
  float4 acc[BB];
  #pragma unroll
  for (int b=0; b<BB; ++b){ acc[b].x=0.f; acc[b].y=0.f; acc[b].z=0.f; acc[b].w=0.f; }
  const float* Ac = A_ + (size_t)mbase*NN + n0 + t*4;
  for (int ml=0; ml<G2_MT; ++ml){
    float4 a4 = *(const float4*)(Ac + (size_t)ml*NN);
    #pragma unroll
    for (int b=0; b<BB; ++b){
      float s = zs[b][ml];
      acc[b].x += a4.x*s; acc[b].y += a4.y*s; acc[b].z += a4.z*s; acc[b].w += a4.w*s;
    }
  }
  #pragma unroll
  for (int b=0; b<BB; ++b)
    *(float4*)&up[((size_t)ms*BB + b)*NN + n0 + t*4] = acc[b];
}

// ------------- combine: x = clip(x - beta*(rk + sum_ms up[ms]), 0, 1) -------------
__global__ __launch_bounds__(256) void k_combine(float* __restrict__ x,
                                                 const float* __restrict__ rk,
                                                 const float* __restrict__ up,
                                                 const float* __restrict__ beta){
  int idx = blockIdx.x*256 + threadIdx.x;           // BB*NN/4 = 32768
  if (idx >= BB*NN/4) return;
  float bta = clamp02(beta[0]);
  float4 acc = *(const float4*)&rk[idx*4];
  #pragma unroll 8
  for (int ms=0; ms<G2_MS; ++ms){
    float4 u4 = *(const float4*)&up[(size_t)ms*BB*NN + idx*4];
    acc.x += u4.x; acc.y += u4.y; acc.z += u4.z; acc.w += u4.w;
  }
  float4 xv = *(const float4*)&x[idx*4];
  xv.x = clamp01(xv.x - bta*acc.x);
  xv.y = clamp01(xv.y - bta*acc.y);
  xv.z = clamp01(xv.z - bta*acc.z);
  xv.w = clamp01(xv.w - bta*acc.w);
  *(float4*)&x[idx*4] = xv;
}

extern "C" void kernel_launch(void* const* d_in, const int* in_sizes, int n_in,
                              void* d_out, int out_size, void* d_ws, size_t ws_size,
                              hipStream_t stream) {
  const float* d_d   = (const float*)d_in[0];
  const float* d_A   = (const float*)d_in[1];
  const float* w1    = (const float*)d_in[2];
  const float* b1    = (const float*)d_in[3];
  const float* w2    = (const float*)d_in[4];
  const float* b2    = (const float*)d_in[5];
  const float* w3    = (const float*)d_in[6];
  const float* b3    = (const float*)d_in[7];
  const float* wK    = (const float*)d_in[8];
  const float* delta = (const float*)d_in[9];
  const float* alpha = (const float*)d_in[10];
  // d_in[11] = lambd (dead in reference after simplification)
  const float* beta  = (const float*)d_in[12];

  float* ws = (float*)d_ws;
  size_t off = 0;
  float* x   = ws + off; off += (size_t)BB*NN;        // 131072
  float* Kx  = ws + off; off += (size_t)BB*KC*NPIX;   // 262144
  float* t1  = ws + off; off += (size_t)BB*KC*NPIX;
  float* t2  = ws + off; off += (size_t)BB*KC*NPIX;
  float* rk1 = ws + off; off += (size_t)BB*NN;        // 131072
  float* y   = ws + off; off += (size_t)BB*MM;        // 32768
  float* z   = ws + off; off += (size_t)BB*MM;
  float* dnb = ws + off; off += 8;
  float* up  = ws + off; off += (size_t)G2_MS*BB*NN;  // 4194304

  hipMemsetAsync(x, 0, (size_t)BB*NN*sizeof(float), stream);
  k_dn<<<BB, 256, 0, stream>>>(d_d, dnb);

  for (int it=0; it<9; ++it){
    k_convK <<<1024, 256, 0, stream>>>(x, wK, Kx);
    k_conv5 <<<1024, 256, 0, stream>>>(Kx, w1, b1, t1, nullptr, nullptr, 0);
    k_conv5 <<<1024, 256, 0, stream>>>(t1, w2, b2, t2, nullptr, nullptr, 0);
    k_conv5 <<<1024, 256, 0, stream>>>(t2, w3, b3, t1, Kx, alpha, 1);   // t1 := 2a(Kx - pk)
    k_convKt<<< 512, 256, 0, stream>>>(t1, wK, rk1);

    hipMemsetAsync(y, 0, (size_t)BB*MM*sizeof(float), stream);
    k_gemm1 <<<(MM/G1_TM)*G1_NS, 256, 0, stream>>>(d_A, x, y);
    k_proj  <<<BB, 256, 0, stream>>>(y, d_d, dnb, delta, alpha, z);
    k_gemm2 <<<G2_MS*G2_NB, 256, 0, stream>>>(d_A, z, up);
    k_combine<<<(BB*NN/4+255)/256, 256, 0, stream>>>(x, rk1, up, beta);
  }

  hipMemcpyAsync(d_out, x, (size_t)BB*NN*sizeof(float), hipMemcpyDeviceToDevice, stream);
}

// Round 2
// 1466.775 us; speedup vs baseline: 1.0089x; 1.0089x over previous
//
#include <hip/hip_runtime.h>
#include <math.h>

#define HH 128
#define NPIX 16384
#define BB 8
#define MM 4096
#define NN 16384
#define KC 2
#define LRELU_S 0.1f

typedef __attribute__((ext_vector_type(8))) short bf16x8;
typedef __attribute__((ext_vector_type(4))) float f32x4;

__device__ __forceinline__ float leaky_(float v){ return v >= 0.f ? v : LRELU_S*v; }
__device__ __forceinline__ float clamp01(float v){ return fminf(fmaxf(v, 0.f), 1.f); }
__device__ __forceinline__ float clamp02(float v){ return fminf(fmaxf(v, 0.f), 2.f); }
__device__ __forceinline__ unsigned short f2bf(float f){
  unsigned u = __float_as_uint(f);
  u = (u + 0x7FFFu + ((u >> 16) & 1u)) >> 16;
  return (unsigned short)u;
}

// ---------- prep: A f32 -> Abf[m][n] bf16  and  Atp[m>>3][n][8] bf16 ----------
__global__ __launch_bounds__(256) void k_prep(const float* __restrict__ A_,
                                              unsigned short* __restrict__ Abf,
                                              unsigned short* __restrict__ Atp){
  __shared__ float lds[64][65];
  int bm = blockIdx.x >> 8, bn = blockIdx.x & 255;   // grid 64*256
  int m0 = bm*64, n0 = bn*64;
  int t = threadIdx.x;
  for (int i=t; i<64*16; i+=256){
    int r = i >> 4, c4 = i & 15;
    float4 v = *(const float4*)&A_[(size_t)(m0+r)*NN + n0 + c4*4];
    lds[r][c4*4+0]=v.x; lds[r][c4*4+1]=v.y; lds[r][c4*4+2]=v.z; lds[r][c4*4+3]=v.w;
  }
  __syncthreads();
  for (int i=t; i<64*16; i+=256){
    int r = i >> 4, c4 = i & 15;
    unsigned short o[4];
    for (int j=0;j<4;++j) o[j] = f2bf(lds[r][c4*4+j]);
    *(uint2*)&Abf[(size_t)(m0+r)*NN + n0 + c4*4] = *(uint2*)o;
  }
  for (int i=t; i<8*64; i+=256){
    int mbl = i >> 6, nl = i & 63;
    unsigned short o[8];
    for (int j=0;j<8;++j) o[j] = f2bf(lds[mbl*8+j][nl]);
    *(uint4*)&Atp[((size_t)(m0/8 + mbl)*NN + n0 + nl)*8] = *(uint4*)o;
  }
}

// ---------- dn[b] = ||d[b,:]|| ----------
__global__ __launch_bounds__(256) void k_dn(const float* __restrict__ d, float* __restrict__ dn){
  int b = blockIdx.x, t = threadIdx.x;
  float ss = 0.f;
  for (int m=t; m<MM; m+=256){ float v = d[b*MM + m]; ss += v*v; }
  #pragma unroll
  for (int off=32; off; off>>=1) ss += __shfl_down(ss, off);
  __shared__ float red[4];
  if ((t & 63) == 0) red[t>>6] = ss;
  __syncthreads();
  if (t == 0) dn[b] = sqrtf(red[0]+red[1]+red[2]+red[3]);
}

// ---------- fused conv chain: x -> rk1 (convK, 3x res-conv5, scale, convKt) ----------
__global__ __launch_bounds__(256) void k_conv_chain(const float* __restrict__ x,
    const float* __restrict__ wK, const float* __restrict__ w1, const float* __restrict__ b1,
    const float* __restrict__ w2, const float* __restrict__ b2,
    const float* __restrict__ w3, const float* __restrict__ b3,
    const float* __restrict__ alpha, float* __restrict__ rk){
  __shared__ float xs[24][128];
  __shared__ float bufA[2][22][128];
  __shared__ float bufB[2][18][128];
  __shared__ float wKs[18], w1s[100], w2s[100], w3s[100], bs[3][2];
  __shared__ float twoa;
  int blk = blockIdx.x;              // 128 = 8 b * 16 slabs
  int b = blk >> 4, slab = blk & 15, r0 = slab*8;
  int t = threadIdx.x;
  for (int i=t;i<18;i+=256) wKs[i]=wK[i];
  for (int i=t;i<100;i+=256){ w1s[i]=w1[i]; w2s[i]=w2[i]; w3s[i]=w3[i]; }
  if (t<2){ bs[0][t]=b1[t]; bs[1][t]=b2[t]; bs[2][t]=b3[t]; }
  if (t==0) twoa = 2.f*clamp02(alpha[0]);
  for (int idx=t; idx<24*128; idx+=256){
    int i = idx>>7, j = idx&127, ir = r0-8+i;
    xs[i][j] = ((unsigned)ir < 128u) ? x[b*NPIX + ir*HH + j] : 0.f;
  }
  __syncthreads();
  // Kx -> bufA (22 rows, ir = r0-7+i)
  for (int c=0;c<2;++c)
    for (int idx=t; idx<22*128; idx+=256){
      int i = idx>>7, j = idx&127, ir = r0-7+i;
      float s = 0.f;
      if ((unsigned)ir < 128u){
        #pragma unroll
        for (int di=0;di<3;++di){
          #pragma unroll
          for (int dj=0;dj<3;++dj){
            int jj = j+dj-1;
            if ((unsigned)jj < 128u) s += xs[i+di][jj]*wKs[(c*3+di)*3+dj];
          }
        }
      }
      bufA[c][i][j] = s;
    }
  __syncthreads();
  // s1 -> bufB (18 rows, ir = r0-5+i)
  for (int o=0;o<2;++o)
    for (int idx=t; idx<18*128; idx+=256){
      int i = idx>>7, j = idx&127, ir = r0-5+i;
      float v = 0.f;
      if ((unsigned)ir < 128u){
        float s = bs[0][o];
        #pragma unroll
        for (int c=0;c<2;++c)
          #pragma unroll
          for (int di=0;di<5;++di)
            #pragma unroll
            for (int dj=0;dj<5;++dj){
              int jj = j+dj-2;
              if ((unsigned)jj < 128u) s += bufA[c][i+di][jj]*w1s[(o*2+c)*25+di*5+dj];
            }
        v = bufA[o][i+2][j] + leaky_(s);
      }
      bufB[o][i][j] = v;
    }
  __syncthreads();
  // s2 -> bufA (14 rows, ir = r0-3+i)
  for (int o=0;o<2;++o)
    for (int idx=t; idx<14*128; idx+=256){
      int i = idx>>7, j = idx&127, ir = r0-3+i;
      float v = 0.f;
      if ((unsigned)ir < 128u){
        float s = bs[1][o];
        #pragma unroll
        for (int c=0;c<2;++c)
          #pragma unroll
          for (int di=0;di<5;++di)
            #pragma unroll
            for (int dj=0;dj<5;++dj){
              int jj = j+dj-2;
              if ((unsigned)jj < 128u) s += bufB[c][i+di][jj]*w2s[(o*2+c)*25+di*5+dj];
            }
        v = bufB[o][i+2][j] + leaky_(s);
      }
      bufA[o][i][j] = v;
    }
  __syncthreads();
  // s3 -> bufB (10 rows, ir = r0-1+i)
  for (int o=0;o<2;++o)
    for (int idx=t; idx<10*128; idx+=256){
      int i = idx>>7, j = idx&127, ir = r0-1+i;
      float v = 0.f;
      if ((unsigned)ir < 128u){
        float s = bs[2][o];
        #pragma unroll
        for (int c=0;c<2;++c)
          #pragma unroll
          for (int di=0;di<5;++di)
            #pragma unroll
            for (int dj=0;dj<5;++dj){
              int jj = j+dj-2;
              if ((unsigned)jj < 128u) s += bufA[c][i+di][jj]*w3s[(o*2+c)*25+di*5+dj];
            }
        v = bufA[o][i+2][j] + leaky_(s);
      }
      bufB[o][i][j] = v;
    }
  __syncthreads();
  // nu = 2a*(Kx - s3) -> bufA (10 rows, ir = r0-1+i); Kx recomputed from xs
  for (int c=0;c<2;++c)
    for (int idx=t; idx<10*128; idx+=256){
      int i = idx>>7, j = idx&127, ir = r0-1+i;
      float v = 0.f;
      if ((unsigned)ir < 128u){
        float kx = 0.f;
        #pragma unroll
        for (int di=0;di<3;++di)
          #pragma unroll
          for (int dj=0;dj<3;++dj){
            int jj = j+dj-1;
            if ((unsigned)jj < 128u) kx += xs[i+6+di][jj]*wKs[(c*3+di)*3+dj];
          }
        v = twoa*(kx - bufB[c][i][j]);
      }
      bufA[c][i][j] = v;
    }
  __syncthreads();
  // convKt -> rk (8 rows, ir = r0+i)
  for (int idx=t; idx<8*128; idx+=256){
    int i = idx>>7, j = idx&127, ir = r0+i;
    float s = 0.f;
    #pragma unroll
    for (int c=0;c<2;++c)
      #pragma unroll
      for (int di=0;di<3;++di)
        #pragma unroll
        for (int dj=0;dj<3;++dj){
          int jj = j+dj-1;
          if ((unsigned)jj < 128u) s += bufA[c][i+di][jj]*wKs[(c*3+(2-di))*3+(2-dj)];
        }
    rk[b*NPIX + ir*HH + j] = s;
  }
}

// ---------- gemm1: e[m][16] = (A@x)[m][b] - d[b][m]; dist2p[mt][8] partials ----------
__global__ __launch_bounds__(512) void k_gemm1mf(const unsigned short* __restrict__ Abf,
    const unsigned short* __restrict__ xtt, const float* __restrict__ d_,
    float* __restrict__ e_, float* __restrict__ d2p){
  int mt = blockIdx.x;                 // 256
  int w = threadIdx.x >> 6;            // k-split 0..8
  int lane = threadIdx.x & 63;
  int kg = lane >> 4, col = lane & 15;
  const unsigned short* Ap = Abf + (size_t)(mt*16 + col)*NN + w*2048 + kg*8;
  const unsigned short* Bp = xtt + ((size_t)(w*256 + kg)*16 + col)*8;
  f32x4 acc = {0.f,0.f,0.f,0.f};
  #pragma unroll 8
  for (int s=0; s<64; ++s){
    bf16x8 a = *(const bf16x8*)(Ap + s*32);
    bf16x8 b = *(const bf16x8*)(Bp + s*512);
    acc = __builtin_amdgcn_mfma_f32_16x16x32_bf16(a, b, acc, 0, 0, 0);
  }
  __shared__ float part[8][16][16];
  __shared__ float p2[16][16];
  #pragma unroll
  for (int j=0;j<4;++j) part[w][kg*4+j][col] = acc[j];
  __syncthreads();
  int t = threadIdx.x;
  if (t < 256){
    int r = t >> 4, b = t & 15;
    float s = 0.f;
    #pragma unroll
    for (int w2=0; w2<8; ++w2) s += part[w2][r][b];
    int m = mt*16 + r;
    float ee = s - ((b < 8) ? d_[b*MM + m] : 0.f);
    e_[m*16 + b] = ee;
    p2[r][b] = (b < 8) ? ee*ee : 0.f;
  }
  __syncthreads();
  if (t < 8){
    float s2 = 0.f;
    #pragma unroll
    for (int r2=0;r2<16;++r2) s2 += p2[r2][t];
    d2p[mt*8 + t] = s2;
  }
}

// ---------- zt: reduce dist2 -> coef; zt[m>>3][b16][m&7] = bf16(coef_b * e[m][b]) ----------
__global__ __launch_bounds__(256) void k_zt(const float* __restrict__ e_,
    const float* __restrict__ d2p, const float* __restrict__ dn,
    const float* __restrict__ delta, const float* __restrict__ alpha,
    unsigned short* __restrict__ zt){
  __shared__ float red[32][8];
  __shared__ float cf[8];
  int t = threadIdx.x;
  {
    int b = t & 7, chunk = t >> 3;    // 32 chunks
    float s = 0.f;
    #pragma unroll
    for (int i=0;i<8;++i) s += d2p[(chunk + 32*i)*8 + b];
    red[chunk][b] = s;
  }
  __syncthreads();
  if (t < 8){
    float s2 = 0.f;
    #pragma unroll
    for (int c=0;c<32;++c) s2 += red[c][t];
    float dist = fmaxf(sqrtf(s2), 1e-10f);
    float de = expf(delta[0]);
    float a = clamp02(alpha[0]);
    float scale = fminf(1.f, de*dn[t]/dist);
    cf[t] = 2.f*a*(1.f - scale);
  }
  __syncthreads();
  int m0 = blockIdx.x*128;            // 32 blocks
  for (int idx=t; idx<128*16; idx+=256){
    int ml = idx >> 4, b = idx & 15, m = m0 + ml;
    float v = (b < 8) ? cf[b]*e_[m*16 + b] : 0.f;
    zt[(size_t)(m>>3)*128 + b*8 + (m&7)] = f2bf(v);
  }
}

// ---------- gemm2: up[ms][b16][n] = sum_{m in split} A[m][n]*z[m][b] ----------
__global__ __launch_bounds__(64) void k_gemm2mf(const unsigned short* __restrict__ Atp,
    const unsigned short* __restrict__ zt, float* __restrict__ up){
  int blk = blockIdx.x;               // 2048
  int nt = blk >> 1, ms = blk & 1;
  int lane = threadIdx.x;
  int kg = lane >> 4, nc = lane & 15;
  const unsigned short* Ap = zt  + ((size_t)(ms*256 + kg)*16 + nc)*8;
  const unsigned short* Bp = Atp + ((size_t)(ms*256 + kg)*NN + nt*16 + nc)*8;
  f32x4 acc = {0.f,0.f,0.f,0.f};
  #pragma unroll 8
  for (int s=0; s<64; ++s){
    bf16x8 a = *(const bf16x8*)(Ap + (size_t)s*512);
    bf16x8 b = *(const bf16x8*)(Bp + (size_t)s*4*NN*8);
    acc = __builtin_amdgcn_mfma_f32_16x16x32_bf16(a, b, acc, 0, 0, 0);
  }
  #pragma unroll
  for (int j=0;j<4;++j)
    up[(size_t)(ms*16 + kg*4 + j)*NN + nt*16 + nc] = acc[j];
}

// ---------- combine: x = clip(x - beta*(rk + up0 + up1)); also write xtt bf16-pack ----------
__global__ __launch_bounds__(256) void k_combine2(const float* __restrict__ up,
    const float* __restrict__ rk, const float* __restrict__ beta,
    float* __restrict__ x, unsigned short* __restrict__ xtt){
  int gid = blockIdx.x*256 + threadIdx.x;   // 32768 = 16 b x 2048 nb
  int b = gid >> 11, nb = gid & 2047, n0 = nb*8;
  if (b >= 8){
    uint4 z = {0,0,0,0};
    *(uint4*)&xtt[(size_t)(nb*16 + b)*8] = z;
    return;
  }
  float bta = clamp02(beta[0]);
  float xv[8]; unsigned short o[8];
  #pragma unroll
  for (int j=0;j<8;++j){
    float v = rk[b*NPIX + n0 + j]
            + up[(size_t)(0*16 + b)*NN + n0 + j]
            + up[(size_t)(1*16 + b)*NN + n0 + j];
    xv[j] = clamp01(x[b*NPIX + n0 + j] - bta*v);
    o[j] = f2bf(xv[j]);
  }
  #pragma unroll
  for (int j=0;j<8;++j) x[b*NPIX + n0 + j] = xv[j];
  *(uint4*)&xtt[(size_t)(nb*16 + b)*8] = *(uint4*)o;
}

extern "C" void kernel_launch(void* const* d_in, const int* in_sizes, int n_in,
                              void* d_out, int out_size, void* d_ws, size_t ws_size,
                              hipStream_t stream) {
  const float* d_d   = (const float*)d_in[0];
  const float* d_A   = (const float*)d_in[1];
  const float* w1    = (const float*)d_in[2];
  const float* b1    = (const float*)d_in[3];
  const float* w2    = (const float*)d_in[4];
  const float* b2    = (const float*)d_in[5];
  const float* w3    = (const float*)d_in[6];
  const float* b3    = (const float*)d_in[7];
  const float* wK    = (const float*)d_in[8];
  const float* delta = (const float*)d_in[9];
  const float* alpha = (const float*)d_in[10];
  const float* beta  = (const float*)d_in[12];

  char* p = (char*)d_ws;
  unsigned short* Abf = (unsigned short*)p; p += (size_t)MM*NN*2;      // 128 MiB
  unsigned short* Atp = (unsigned short*)p; p += (size_t)MM*NN*2;      // 128 MiB
  unsigned short* xtt = (unsigned short*)p; p += (size_t)2048*16*8*2;  // 512 KiB
  unsigned short* zt  = (unsigned short*)p; p += (size_t)512*16*8*2;   // 128 KiB
  float* x   = (float*)p; p += (size_t)BB*NPIX*4;
  float* rk1 = (float*)p; p += (size_t)BB*NPIX*4;
  float* e_  = (float*)p; p += (size_t)MM*16*4;
  float* up  = (float*)p; p += (size_t)2*16*NN*4;
  float* d2p = (float*)p; p += (size_t)256*8*4;
  float* dnb = (float*)p; p += 64;

  k_prep<<<64*256, 256, 0, stream>>>(d_A, Abf, Atp);
  k_dn<<<BB, 256, 0, stream>>>(d_d, dnb);
  hipMemsetAsync(x, 0, (size_t)BB*NPIX*4, stream);
  hipMemsetAsync(xtt, 0, (size_t)2048*16*8*2, stream);

  for (int it=0; it<9; ++it){
    k_conv_chain<<<128, 256, 0, stream>>>(x, wK, w1, b1, w2, b2, w3, b3, alpha, rk1);
    k_gemm1mf<<<256, 512, 0, stream>>>(Abf, xtt, d_d, e_, d2p);
    k_zt<<<32, 256, 0, stream>>>(e_, d2p, dnb, delta, alpha, zt);
    k_gemm2mf<<<2048, 64, 0, stream>>>(Atp, zt, up);
    k_combine2<<<128, 256, 0, stream>>>(up, rk1, beta, x, xtt);
  }

  hipMemcpyAsync(d_out, x, (size_t)BB*NPIX*4, hipMemcpyDeviceToDevice, stream);
}